// Round 7
// baseline (797.744 us; speedup 1.0000x reference)
//
#include <hip/hip_runtime.h>
#include <cfloat>
#include <math.h>

// Problem constants
constexpr int H_  = 6;
constexpr int C_  = 64;
constexpr int OV_ = 4;
constexpr int G_  = 3;
constexpr int NVQ_ = 6;
constexpr int K_  = 1024;
constexpr int D_  = 8;
constexpr int B_  = 32;
constexpr int W_  = 2400;
constexpr int T_  = 600;          // W/OV
constexpr int NPOS_ = B_ * T_;    // 19200
constexpr int FIX_ = H_ * C_;     // 384
constexpr int GD_ = 512;

// Output layout (floats, concatenated in return order)
constexpr size_t OUT_ZQ   = 0;
constexpr size_t OUT_IDX  = (size_t)B_ * H_ * W_ * C_;             // 29491200
constexpr size_t OUT_LOSS = OUT_IDX + (size_t)B_ * NVQ_ * G_ * T_; // 29836800

// Workspace layout (bytes) — IDENTICAL to the 758 µs baseline layout.
constexpr size_t WS_EN   = 0;                                   // double[18*1024*8] ROW-major [gi][k][d]
constexpr size_t WS_ZD   = WS_EN + (size_t)G_*NVQ_*K_*D_*8;     // double[3*19200*8]
constexpr size_t WS_LOSS = WS_ZD + (size_t)G_*NPOS_*D_*8;       // double[8]
constexpr size_t WS_ZQ   = WS_LOSS + 64;                        // float[3*19200*8]

// fp32 row-major codebook scratch lives in the OUTPUT buffer (first 576 KB of
// the zq region): written by k1, read by k3, fully overwritten by k4 later.

// ---------------------------------------------------------------------------
// K1: normalize codebooks (fp64); write row-major fp64 [gi][k][d] and fp32
//     [gi][k][d] copies; zero the loss accumulator.
__global__ __launch_bounds__(256) void k1_norm_cb(const float* __restrict__ cb,
                                                  double* __restrict__ en,
                                                  float* __restrict__ en32,
                                                  double* __restrict__ loss) {
    int tid = blockIdx.x * 256 + threadIdx.x;
    if (tid == 0) loss[0] = 0.0;
    if (tid >= G_ * NVQ_ * K_) return;
    int k  = tid & (K_ - 1);
    int gi = tid >> 10;               // 0..17  (g*6+i)
    const float* row = cb + ((size_t)gi * K_ + k) * D_;
    double v[D_];
    double ss = 0.0;
#pragma unroll
    for (int d = 0; d < D_; d++) { v[d] = (double)row[d]; ss += v[d] * v[d]; }
    double n = sqrt(ss);
    if (n < 1e-12) n = 1e-12;
    double* dst64 = en + ((size_t)gi * K_ + k) * D_;
    float*  dst32 = en32 + ((size_t)gi * K_ + k) * D_;
#pragma unroll
    for (int d = 0; d < D_; d++) {
        double q = v[d] / n;          // division to mimic ref
        dst64[d] = q;
        dst32[d] = (float)q;
    }
}

// ---------------------------------------------------------------------------
// K2: fold (pre_process) + proj_down, fp64 accumulation in 4 interleaved
// partials (breaks the 512-deep serial dfma chain; fixed final sum order).
constexpr int PSTR_ = 1548;
constexpr int OVS_  = 388;

__global__ __launch_bounds__(256) void k2_fold_pd(const float* __restrict__ ze,
                                                  const float* __restrict__ pd,
                                                  double* __restrict__ zd) {
    __shared__ __align__(16) float zf[8 * PSTR_];
    int tid  = threadIdx.x;
    int pos0 = blockIdx.x * 8;
#pragma unroll
    for (int it = 0; it < 12; it++) {
        int slot = it * 256 + tid;
        int seg  = slot >> 6;
        int li   = slot & 63;
        int p = seg / 6, h = seg - p * 6;
        int pos = pos0 + p;
        int b = pos / T_, t = pos - b * T_;
        const float4 vv = *(const float4*)(ze + ((size_t)((b * H_ + h) * W_ + 4 * t)) * C_ + li * 4);
        int ov = li >> 4;
        int c0 = (li & 15) * 4;
        int base = p * PSTR_ + ov * OVS_ + h;
        zf[base + (c0 + 0) * 6] = vv.x;
        zf[base + (c0 + 1) * 6] = vv.y;
        zf[base + (c0 + 2) * 6] = vv.z;
        zf[base + (c0 + 3) * 6] = vv.w;
    }
    __syncthreads();
    if (tid < 192) {
        int p = tid / 24;
        int combo = tid - p * 24;
        int g = combo >> 3, d = combo & 7;
        const float* pdp = pd + ((size_t)g * D_ + d) * GD_;
        int lbase = p * PSTR_;
        double acc[4] = {0.0, 0.0, 0.0, 0.0};
        for (int jj = 0; jj < GD_; jj += 16) {
#pragma unroll
            for (int u = 0; u < 4; u++) {
                int j4  = jj + u * 4;
                int gd  = g * GD_ + j4;
                int ov  = gd / FIX_;
                int rem = gd - ov * FIX_;
                float4 zv = *(const float4*)&zf[lbase + ov * OVS_ + rem];
                float4 pv = *(const float4*)&pdp[j4];
                acc[u] = fma((double)pv.x, (double)zv.x, acc[u]);
                acc[u] = fma((double)pv.y, (double)zv.y, acc[u]);
                acc[u] = fma((double)pv.z, (double)zv.z, acc[u]);
                acc[u] = fma((double)pv.w, (double)zv.w, acc[u]);
            }
        }
        zd[((size_t)g * NPOS_ + pos0 + p) * D_ + d] = (acc[0] + acc[1]) + (acc[2] + acc[3]);
    }
}

// ---------------------------------------------------------------------------
// K3 v4: lane-owns-chain with IN-WAVE k-split. Lane l: chain = l>>2 (16
// chains/wave, 4-fold lane-replicated), k-phase j = l&3, scans k = 4c+j.
// Per step the wave touches one contiguous 128 B codeword line (VMEM,
// L1/L2-resident). Merge = 2 shfl_xor steps. ZERO barriers, ZERO LDS:
// waves fully independent -> phase decorrelation hides gather latency
// (round-6 lesson: phase-locked cross-wave merge capped VALUBusy at 50%).
// Any fp32 ambiguity (incl. ties) fails the gap test -> exact fp64 rescan
// with wave-uniform k (scalar loads), so final indices == fp64 argmax.
__device__ __forceinline__ void screen1(const float4 lo, const float4 hi,
                                        const float r[8], int kk,
                                        float& smax, float& s2, int& sidx) {
    float s = lo.x * r[0];
    s = fmaf(lo.y, r[1], s);
    s = fmaf(lo.z, r[2], s);
    s = fmaf(lo.w, r[3], s);
    s = fmaf(hi.x, r[4], s);
    s = fmaf(hi.y, r[5], s);
    s = fmaf(hi.z, r[6], s);
    s = fmaf(hi.w, r[7], s);
    float l = fminf(s, smax);
    s2 = fmaxf(s2, l);
    if (s > smax) { smax = s; sidx = kk; }   // strict >: first index wins
}

__global__ __launch_bounds__(256) void k3_rvq(const double* __restrict__ en64,
                                              const float*  __restrict__ en32,
                                              const double* __restrict__ zd,
                                              float* __restrict__ zq,
                                              double* __restrict__ loss,
                                              float* __restrict__ out_idx) {
    int tid  = threadIdx.x;
    int lane = tid & 63;
    int gw   = blockIdx.x * 4 + (tid >> 6);   // global wave id 0..3599
    int g     = gw / 1200;
    int batch = gw - g * 1200;                // 0..1199
    int cw = lane >> 2;                       // chain-in-wave 0..15
    int j  = lane & 3;                        // k-phase 0..3
    int pos = batch * 16 + cw;                // this lane's chain
    size_t zdbase = ((size_t)g * NPOS_ + pos) * D_;

    const double* en64g = en64 + (size_t)g * NVQ_ * K_ * D_;
    const float*  en32g = en32 + (size_t)g * NVQ_ * K_ * D_;

    // exact fp64 residual (replicated across the 4 lanes of each chain)
    double r64[8]; float r32[8];
    {
        const double* zp = zd + zdbase;
#pragma unroll
        for (int d = 0; d < 8; d++) { r64[d] = zp[d]; r32[d] = (float)r64[d]; }
    }
    double loss_acc = 0.0;

    for (int i = 0; i < NVQ_; i++) {
        // ---- fp32 screen: lane scans k = 4c + j, c = 0..255 (stride 128 B)
        const float* cp = en32g + ((size_t)i * K_ + j) * D_;
        float smax = -FLT_MAX, s2 = -FLT_MAX; int sidx = 0;
#pragma unroll 4
        for (int c = 0; c < 256; c++) {
            const float4* q = (const float4*)(cp + (size_t)c * 32);
            float4 a = q[0], b = q[1];
            screen1(a, b, r32, c * 4 + j, smax, s2, sidx);
        }
        // ---- in-wave merge across the 4 k-phases (xor 1, then 2)
#pragma unroll
        for (int off = 1; off <= 2; off <<= 1) {
            float om = __shfl_xor(smax, off);
            int   oi = __shfl_xor(sidx, off);
            float o2 = __shfl_xor(s2, off);
            s2 = fmaxf(fmaxf(s2, o2), fminf(smax, om));
            if (om > smax || (om == smax && oi < sidx)) { smax = om; sidx = oi; }
        }
        // ---- certify winner vs fp64; rescan exactly if gap can't prove it.
        // |s32 - s64| <= ~10*2^-24*||r||; require gap > 4e-6*||r|| (3x margin)
        float rr = 0.f;
#pragma unroll
        for (int d = 0; d < 8; d++) rr = fmaf(r32[d], r32[d], rr);
        float gap = smax - s2;
        bool need = !(gap * gap > 1.6e-11f * rr);
        if (__any(need)) {                    // rare; k loop is wave-uniform
            const double* bp = en64g + (size_t)i * K_ * D_;
            double bmax = -DBL_MAX; int bidx = 0;
            for (int k = 0; k < K_; k++) {
                const double* cq = bp + (size_t)k * 8;   // uniform -> s_load
                double sA = cq[0] * r64[0];
                double sB = cq[1] * r64[1];
                sA = fma(cq[2], r64[2], sA);
                sB = fma(cq[3], r64[3], sB);
                sA = fma(cq[4], r64[4], sA);
                sB = fma(cq[5], r64[5], sB);
                sA = fma(cq[6], r64[6], sA);
                sB = fma(cq[7], r64[7], sB);
                double s = sA + sB;
                if (s > bmax) { bmax = s; bidx = k; }
            }
            if (need) sidx = bidx;
        }
        // ---- exact fp64 update (per lane; 64 B contiguous gather, 16 unique)
        {
            const double* qp = en64g + ((size_t)i * K_ + sidx) * D_;
            double2 q01 = *(const double2*)(qp + 0);
            double2 q23 = *(const double2*)(qp + 2);
            double2 q45 = *(const double2*)(qp + 4);
            double2 q67 = *(const double2*)(qp + 6);
            r64[0] -= q01.x; r64[1] -= q01.y;
            r64[2] -= q23.x; r64[3] -= q23.y;
            r64[4] -= q45.x; r64[5] -= q45.y;
            r64[6] -= q67.x; r64[7] -= q67.y;
#pragma unroll
            for (int d = 0; d < 8; d++) r32[d] = (float)r64[d];
        }
        if (j == 0) {
#pragma unroll
            for (int d = 0; d < 8; d++) loss_acc = fma(r64[d], r64[d], loss_acc);
            int b = pos / T_, t = pos - b * T_;
            out_idx[((size_t)(b * NVQ_ + i) * G_ + g) * T_ + t] = (float)sidx;
        }
    }
    // ---- epilogue: j==0 lanes write zq; wave-reduce loss (j!=0 lanes hold 0)
    if (j == 0) {
        const double* zp = zd + zdbase;
        float4 o0, o1;
        o0.x = (float)(zp[0] - r64[0]);
        o0.y = (float)(zp[1] - r64[1]);
        o0.z = (float)(zp[2] - r64[2]);
        o0.w = (float)(zp[3] - r64[3]);
        o1.x = (float)(zp[4] - r64[4]);
        o1.y = (float)(zp[5] - r64[5]);
        o1.z = (float)(zp[6] - r64[6]);
        o1.w = (float)(zp[7] - r64[7]);
        *(float4*)(zq + zdbase)     = o0;
        *(float4*)(zq + zdbase + 4) = o1;
    }
#pragma unroll
    for (int off = 32; off >= 1; off >>= 1) loss_acc += __shfl_xor(loss_acc, off);
    if (lane == 0) atomicAdd(loss, loss_acc);
}

// ---------------------------------------------------------------------------
// K4: proj_up + unfold scatter (fp32). pu_s NATURAL stride-8 rows (16B
// aligned -> ds_read_b128) with XOR swizzle byte^=((byte>>8)&7)<<4
// (bijective involution). Round-6 verified: ~80 µs faster than stride-9.
__device__ __forceinline__ int swz48(int byte) {
    return byte ^ (((byte >> 8) & 7) << 4);
}

__global__ __launch_bounds__(512) void k4_up(const float* __restrict__ zq,
                                             const float* __restrict__ pu,
                                             const double* __restrict__ loss,
                                             float* __restrict__ out_zq,
                                             float* __restrict__ out_loss) {
    __shared__ __align__(16) float pu_s[G_ * GD_ * 8];   // 48 KB, swizzled
    char* pb = (char*)pu_s;
    int tid = threadIdx.x;
#pragma unroll
    for (int it = 0; it < 3; it++) {
        int row = it * 512 + tid;            // 0..1535
        float4 lo = *(const float4*)(pu + (size_t)row * 8);
        float4 hi = *(const float4*)(pu + (size_t)row * 8 + 4);
        int byte0 = row * 32;
        *(float4*)(pb + swz48(byte0))      = lo;
        *(float4*)(pb + swz48(byte0 + 16)) = hi;
    }
    if (blockIdx.x == 0 && tid == 0) {
        double l = loss[0] * (1.0 / 460800.0);   // /(B*T*D) per group, /G
        out_loss[0] = (float)l;
        out_loss[1] = (float)l;
    }
    __syncthreads();
    int wv = tid >> 6, lane = tid & 63;
    int pos = blockIdx.x * 8 + wv;
    int b = pos / T_, t = pos - b * T_;
    int ov = lane >> 4, c0 = (lane & 15) * 4;
    int gd_min = ov * FIX_ + c0 * 6;
    int g_lo = gd_min >> 9;
    int g_hi = g_lo < 2 ? g_lo + 1 : 2;
    float za[8], zb[8];
    const float* zqa = zq + ((size_t)g_lo * NPOS_ + pos) * D_;
    const float* zqb = zq + ((size_t)g_hi * NPOS_ + pos) * D_;
#pragma unroll
    for (int d = 0; d < 8; d++) { za[d] = zqa[d]; zb[d] = zqb[d]; }
#pragma unroll
    for (int h = 0; h < H_; h++) {
        float4 o;
        float* op = &o.x;
#pragma unroll
        for (int q = 0; q < 4; q++) {
            int gd = ov * FIX_ + (c0 + q) * 6 + h;   // == row in pu_s
            int byte0 = gd * 32;
            float4 fa = *(const float4*)(pb + swz48(byte0));
            float4 fb = *(const float4*)(pb + swz48(byte0 + 16));
            bool hi = ((gd >> 9) != g_lo);
            const float* zv = hi ? zb : za;
            float acc = zv[0] * fa.x;
            acc = fmaf(zv[1], fa.y, acc);
            acc = fmaf(zv[2], fa.z, acc);
            acc = fmaf(zv[3], fa.w, acc);
            acc = fmaf(zv[4], fb.x, acc);
            acc = fmaf(zv[5], fb.y, acc);
            acc = fmaf(zv[6], fb.z, acc);
            acc = fmaf(zv[7], fb.w, acc);
            op[q] = acc;
        }
        *(float4*)(out_zq + ((size_t)((b * H_ + h) * W_ + 4 * t + ov)) * C_ + c0) = o;
    }
}

// ---------------------------------------------------------------------------
extern "C" void kernel_launch(void* const* d_in, const int* in_sizes, int n_in,
                              void* d_out, int out_size, void* d_ws, size_t ws_size,
                              hipStream_t stream) {
    const float* ze = (const float*)d_in[0];
    const float* pd = (const float*)d_in[1];
    const float* pu = (const float*)d_in[2];
    const float* cb = (const float*)d_in[3];
    // d_in[4] = num_streams (==6, compile-time NVQ_)

    float* out = (float*)d_out;
    char*  ws  = (char*)d_ws;
    double* ws_en   = (double*)(ws + WS_EN);
    double* ws_zd   = (double*)(ws + WS_ZD);
    double* ws_loss = (double*)(ws + WS_LOSS);
    float*  ws_zq   = (float*)(ws + WS_ZQ);
    // fp32 row-major codebook scratch inside the output zq region (576 KB),
    // fully overwritten by k4 after k3 consumes it.
    float* en32 = out + OUT_ZQ;

    k1_norm_cb<<<(G_ * NVQ_ * K_ + 255) / 256, 256, 0, stream>>>(cb, ws_en, en32, ws_loss);
    k2_fold_pd<<<NPOS_ / 8, 256, 0, stream>>>(ze, pd, ws_zd);
    k3_rvq<<<900, 256, 0, stream>>>(ws_en, en32, ws_zd, ws_zq, ws_loss, out + OUT_IDX);
    k4_up<<<NPOS_ / 8, 512, 0, stream>>>(ws_zq, pu, ws_loss, out + OUT_ZQ, out + OUT_LOSS);
}

// Round 8
// 676.486 us; speedup vs baseline: 1.1792x; 1.1792x over previous
//
#include <hip/hip_runtime.h>
#include <cfloat>
#include <math.h>

// Problem constants
constexpr int H_  = 6;
constexpr int C_  = 64;
constexpr int OV_ = 4;
constexpr int G_  = 3;
constexpr int NVQ_ = 6;
constexpr int K_  = 1024;
constexpr int D_  = 8;
constexpr int B_  = 32;
constexpr int W_  = 2400;
constexpr int T_  = 600;          // W/OV
constexpr int NPOS_ = B_ * T_;    // 19200
constexpr int FIX_ = H_ * C_;     // 384
constexpr int GD_ = 512;

// Output layout (floats, concatenated in return order)
constexpr size_t OUT_ZQ   = 0;
constexpr size_t OUT_IDX  = (size_t)B_ * H_ * W_ * C_;             // 29491200
constexpr size_t OUT_LOSS = OUT_IDX + (size_t)B_ * NVQ_ * G_ * T_; // 29836800

// Workspace layout (bytes) — IDENTICAL to the 758 µs baseline layout.
constexpr size_t WS_EN   = 0;                                   // double[18*1024*8] ROW-major [gi][k][d]
constexpr size_t WS_ZD   = WS_EN + (size_t)G_*NVQ_*K_*D_*8;     // double[3*19200*8]
constexpr size_t WS_LOSS = WS_ZD + (size_t)G_*NPOS_*D_*8;       // double[8]
constexpr size_t WS_ZQ   = WS_LOSS + 64;                        // float[3*19200*8]

// fp32 row-major codebook scratch lives in the OUTPUT buffer (first 576 KB of
// the zq region): written by k1, read by k3, fully overwritten by k4 later.

// ---------------------------------------------------------------------------
// K1: normalize codebooks (fp64); write row-major fp64 [gi][k][d] and fp32
//     [gi][k][d] copies; zero the loss accumulator.
__global__ __launch_bounds__(256) void k1_norm_cb(const float* __restrict__ cb,
                                                  double* __restrict__ en,
                                                  float* __restrict__ en32,
                                                  double* __restrict__ loss) {
    int tid = blockIdx.x * 256 + threadIdx.x;
    if (tid == 0) loss[0] = 0.0;
    if (tid >= G_ * NVQ_ * K_) return;
    int k  = tid & (K_ - 1);
    int gi = tid >> 10;               // 0..17  (g*6+i)
    const float* row = cb + ((size_t)gi * K_ + k) * D_;
    double v[D_];
    double ss = 0.0;
#pragma unroll
    for (int d = 0; d < D_; d++) { v[d] = (double)row[d]; ss += v[d] * v[d]; }
    double n = sqrt(ss);
    if (n < 1e-12) n = 1e-12;
    double* dst64 = en + ((size_t)gi * K_ + k) * D_;
    float*  dst32 = en32 + ((size_t)gi * K_ + k) * D_;
#pragma unroll
    for (int d = 0; d < D_; d++) {
        double q = v[d] / n;          // division to mimic ref
        dst64[d] = q;
        dst32[d] = (float)q;
    }
}

// ---------------------------------------------------------------------------
// K2: fold (pre_process) + proj_down, fp64 accumulation in 4 interleaved
// partials (breaks the 512-deep serial dfma chain; fixed final sum order).
constexpr int PSTR_ = 1548;
constexpr int OVS_  = 388;

__global__ __launch_bounds__(256) void k2_fold_pd(const float* __restrict__ ze,
                                                  const float* __restrict__ pd,
                                                  double* __restrict__ zd) {
    __shared__ __align__(16) float zf[8 * PSTR_];
    int tid  = threadIdx.x;
    int pos0 = blockIdx.x * 8;
#pragma unroll
    for (int it = 0; it < 12; it++) {
        int slot = it * 256 + tid;
        int seg  = slot >> 6;
        int li   = slot & 63;
        int p = seg / 6, h = seg - p * 6;
        int pos = pos0 + p;
        int b = pos / T_, t = pos - b * T_;
        const float4 vv = *(const float4*)(ze + ((size_t)((b * H_ + h) * W_ + 4 * t)) * C_ + li * 4);
        int ov = li >> 4;
        int c0 = (li & 15) * 4;
        int base = p * PSTR_ + ov * OVS_ + h;
        zf[base + (c0 + 0) * 6] = vv.x;
        zf[base + (c0 + 1) * 6] = vv.y;
        zf[base + (c0 + 2) * 6] = vv.z;
        zf[base + (c0 + 3) * 6] = vv.w;
    }
    __syncthreads();
    if (tid < 192) {
        int p = tid / 24;
        int combo = tid - p * 24;
        int g = combo >> 3, d = combo & 7;
        const float* pdp = pd + ((size_t)g * D_ + d) * GD_;
        int lbase = p * PSTR_;
        double acc[4] = {0.0, 0.0, 0.0, 0.0};
        for (int jj = 0; jj < GD_; jj += 16) {
#pragma unroll
            for (int u = 0; u < 4; u++) {
                int j4  = jj + u * 4;
                int gd  = g * GD_ + j4;
                int ov  = gd / FIX_;
                int rem = gd - ov * FIX_;
                float4 zv = *(const float4*)&zf[lbase + ov * OVS_ + rem];
                float4 pv = *(const float4*)&pdp[j4];
                acc[u] = fma((double)pv.x, (double)zv.x, acc[u]);
                acc[u] = fma((double)pv.y, (double)zv.y, acc[u]);
                acc[u] = fma((double)pv.z, (double)zv.z, acc[u]);
                acc[u] = fma((double)pv.w, (double)zv.w, acc[u]);
            }
        }
        zd[((size_t)g * NPOS_ + pos0 + p) * D_ + d] = (acc[0] + acc[1]) + (acc[2] + acc[3]);
    }
}

// ---------------------------------------------------------------------------
// K3 v5: scalar-pipe codebook (round-5 winner) + 2 chains/lane, k-split x8.
// Block: 512 threads (8 waves), 128 positions. Lane l owns chains pos0+l and
// pos0+64+l; wave wu scans k in [wu*128, wu*128+128) via wave-uniform s_load.
// Per wave per stream: 2048 FMA fed by 128 scalar loads (1:16 vs v2's 1:8) —
// halves the s_load stall that capped v2 at 52% VALUBusy; 2 independent dot
// chains double per-lane ILP. Merge: parity double-buffered LDS table, 8-way,
// one barrier/stream. Decisions bit-identical (same margin cert, tie-breaks,
// fp64 update); round-7 lesson: codebook must stay on the scalar pipe.
__device__ __forceinline__ void screen1(const float4 lo, const float4 hi,
                                        const float r[8], int kk,
                                        float& smax, float& s2, int& sidx) {
    float s = lo.x * r[0];
    s = fmaf(lo.y, r[1], s);
    s = fmaf(lo.z, r[2], s);
    s = fmaf(lo.w, r[3], s);
    s = fmaf(hi.x, r[4], s);
    s = fmaf(hi.y, r[5], s);
    s = fmaf(hi.z, r[6], s);
    s = fmaf(hi.w, r[7], s);
    float l = fminf(s, smax);
    s2 = fmaxf(s2, l);
    if (s > smax) { smax = s; sidx = kk; }   // strict >: first index wins
}

__global__ __launch_bounds__(512) void k3_rvq(const double* __restrict__ en64,
                                              const float*  __restrict__ en32,
                                              const double* __restrict__ zd,
                                              float* __restrict__ zq,
                                              double* __restrict__ loss,
                                              float* __restrict__ out_idx) {
    __shared__ float smL[2][8][128];
    __shared__ float s2L[2][8][128];
    __shared__ int   idL[2][8][128];
    int tid  = threadIdx.x;
    int lane = tid & 63;
    int wu   = __builtin_amdgcn_readfirstlane(tid >> 6);  // wave id -> uniform k base
    int g     = blockIdx.x / 150;
    int chunk = blockIdx.x - g * 150;
    int pos0  = chunk * 128;
    int posA  = pos0 + lane;
    int posB  = pos0 + 64 + lane;
    size_t baseA = ((size_t)g * NPOS_ + posA) * D_;
    size_t baseB = ((size_t)g * NPOS_ + posB) * D_;

    const double* en64g = en64 + (size_t)g * NVQ_ * K_ * D_;
    const float*  en32g = en32 + (size_t)g * NVQ_ * K_ * D_;

    // exact fp64 residuals, 2 chains/lane (replicated across the 8 waves)
    double rA[8], rB[8]; float fA[8], fB[8];
    {
        const double* zA = zd + baseA;
        const double* zB = zd + baseB;
#pragma unroll
        for (int d = 0; d < 8; d++) {
            rA[d] = zA[d]; fA[d] = (float)rA[d];
            rB[d] = zB[d]; fB[d] = (float)rB[d];
        }
    }
    double loss_acc = 0.0;

    for (int i = 0; i < NVQ_; i++) {
        int p = i & 1;
        // ---- fp32 screen over this wave's 128 k (wave-uniform scalar loads)
        int kb = wu * 128;
        const float* cp = en32g + ((size_t)i * K_ + kb) * D_;
        float smA = -FLT_MAX, s2A = -FLT_MAX; int siA = 0;
        float smB = -FLT_MAX, s2B = -FLT_MAX; int siB = 0;
        for (int c = 0; c < 128; c += 8) {
            const float4* q0 = (const float4*)(cp + (size_t)(c + 0) * 8);
            const float4* q1 = (const float4*)(cp + (size_t)(c + 1) * 8);
            const float4* q2 = (const float4*)(cp + (size_t)(c + 2) * 8);
            const float4* q3 = (const float4*)(cp + (size_t)(c + 3) * 8);
            const float4* q4 = (const float4*)(cp + (size_t)(c + 4) * 8);
            const float4* q5 = (const float4*)(cp + (size_t)(c + 5) * 8);
            const float4* q6 = (const float4*)(cp + (size_t)(c + 6) * 8);
            const float4* q7 = (const float4*)(cp + (size_t)(c + 7) * 8);
            float4 a0 = q0[0], b0 = q0[1];
            float4 a1 = q1[0], b1 = q1[1];
            float4 a2 = q2[0], b2 = q2[1];
            float4 a3 = q3[0], b3 = q3[1];
            float4 a4 = q4[0], b4 = q4[1];
            float4 a5 = q5[0], b5 = q5[1];
            float4 a6 = q6[0], b6 = q6[1];
            float4 a7 = q7[0], b7 = q7[1];
            screen1(a0, b0, fA, kb + c + 0, smA, s2A, siA);
            screen1(a0, b0, fB, kb + c + 0, smB, s2B, siB);
            screen1(a1, b1, fA, kb + c + 1, smA, s2A, siA);
            screen1(a1, b1, fB, kb + c + 1, smB, s2B, siB);
            screen1(a2, b2, fA, kb + c + 2, smA, s2A, siA);
            screen1(a2, b2, fB, kb + c + 2, smB, s2B, siB);
            screen1(a3, b3, fA, kb + c + 3, smA, s2A, siA);
            screen1(a3, b3, fB, kb + c + 3, smB, s2B, siB);
            screen1(a4, b4, fA, kb + c + 4, smA, s2A, siA);
            screen1(a4, b4, fB, kb + c + 4, smB, s2B, siB);
            screen1(a5, b5, fA, kb + c + 5, smA, s2A, siA);
            screen1(a5, b5, fB, kb + c + 5, smB, s2B, siB);
            screen1(a6, b6, fA, kb + c + 6, smA, s2A, siA);
            screen1(a6, b6, fB, kb + c + 6, smB, s2B, siB);
            screen1(a7, b7, fA, kb + c + 7, smA, s2A, siA);
            screen1(a7, b7, fB, kb + c + 7, smB, s2B, siB);
        }
        smL[p][wu][lane] = smA;  s2L[p][wu][lane] = s2A;  idL[p][wu][lane] = siA;
        smL[p][wu][64 + lane] = smB;  s2L[p][wu][64 + lane] = s2B;  idL[p][wu][64 + lane] = siB;
        __syncthreads();
        // ---- merge the 8 wave-candidates (all waves compute identically;
        //      w ascending = k ascending, strict > keeps smallest k)
        float gsmA = smL[p][0][lane], gs2A = s2L[p][0][lane];
        int   gsiA = idL[p][0][lane];
        float gsmB = smL[p][0][64 + lane], gs2B = s2L[p][0][64 + lane];
        int   gsiB = idL[p][0][64 + lane];
#pragma unroll
        for (int w = 1; w < 8; w++) {
            float a  = smL[p][w][lane];
            float a2 = s2L[p][w][lane];
            int   ai = idL[p][w][lane];
            float l  = fminf(a, gsmA);
            gs2A = fmaxf(gs2A, fmaxf(l, a2));
            if (a > gsmA) { gsmA = a; gsiA = ai; }
            float bsm = smL[p][w][64 + lane];
            float bs2 = s2L[p][w][64 + lane];
            int   bsi = idL[p][w][64 + lane];
            float lb  = fminf(bsm, gsmB);
            gs2B = fmaxf(gs2B, fmaxf(lb, bs2));
            if (bsm > gsmB) { gsmB = bsm; gsiB = bsi; }
        }
        // ---- certify winners vs fp64; rescan exactly if gap can't prove it.
        // |s32 - s64| <= ~10*2^-24*||r||; require gap > 4e-6*||r|| (3x margin)
        float rrA = 0.f, rrB = 0.f;
#pragma unroll
        for (int d = 0; d < 8; d++) {
            rrA = fmaf(fA[d], fA[d], rrA);
            rrB = fmaf(fB[d], fB[d], rrB);
        }
        float gapA = gsmA - gs2A, gapB = gsmB - gs2B;
        bool needA = !(gapA * gapA > 1.6e-11f * rrA);
        bool needB = !(gapB * gapB > 1.6e-11f * rrB);
        if (__any(needA || needB)) {             // rare; k loop is wave-uniform
            const double* bp = en64g + (size_t)i * K_ * D_;
            double bmA = -DBL_MAX, bmB = -DBL_MAX; int biA = 0, biB = 0;
            for (int k = 0; k < K_; k++) {
                const double* cq = bp + (size_t)k * 8;   // uniform -> s_load
                double sA = cq[0] * rA[0];
                double tA = cq[1] * rA[1];
                sA = fma(cq[2], rA[2], sA);
                tA = fma(cq[3], rA[3], tA);
                sA = fma(cq[4], rA[4], sA);
                tA = fma(cq[5], rA[5], tA);
                sA = fma(cq[6], rA[6], sA);
                tA = fma(cq[7], rA[7], tA);
                double dA = sA + tA;
                if (dA > bmA) { bmA = dA; biA = k; }
                double sB = cq[0] * rB[0];
                double tB = cq[1] * rB[1];
                sB = fma(cq[2], rB[2], sB);
                tB = fma(cq[3], rB[3], tB);
                sB = fma(cq[4], rB[4], sB);
                tB = fma(cq[5], rB[5], tB);
                sB = fma(cq[6], rB[6], sB);
                tB = fma(cq[7], rB[7], tB);
                double dB = sB + tB;
                if (dB > bmB) { bmB = dB; biB = k; }
            }
            if (needA) gsiA = biA;
            if (needB) gsiB = biB;
        }
        // ---- exact fp64 update (per lane, both chains; 64 B contiguous gathers)
        {
            const double* qp = en64g + ((size_t)i * K_ + gsiA) * D_;
            double2 q01 = *(const double2*)(qp + 0);
            double2 q23 = *(const double2*)(qp + 2);
            double2 q45 = *(const double2*)(qp + 4);
            double2 q67 = *(const double2*)(qp + 6);
            rA[0] -= q01.x; rA[1] -= q01.y;
            rA[2] -= q23.x; rA[3] -= q23.y;
            rA[4] -= q45.x; rA[5] -= q45.y;
            rA[6] -= q67.x; rA[7] -= q67.y;
            const double* qb = en64g + ((size_t)i * K_ + gsiB) * D_;
            double2 p01 = *(const double2*)(qb + 0);
            double2 p23 = *(const double2*)(qb + 2);
            double2 p45 = *(const double2*)(qb + 4);
            double2 p67 = *(const double2*)(qb + 6);
            rB[0] -= p01.x; rB[1] -= p01.y;
            rB[2] -= p23.x; rB[3] -= p23.y;
            rB[4] -= p45.x; rB[5] -= p45.y;
            rB[6] -= p67.x; rB[7] -= p67.y;
#pragma unroll
            for (int d = 0; d < 8; d++) { fA[d] = (float)rA[d]; fB[d] = (float)rB[d]; }
        }
        if (wu == 0) {
#pragma unroll
            for (int d = 0; d < 8; d++) {
                loss_acc = fma(rA[d], rA[d], loss_acc);
                loss_acc = fma(rB[d], rB[d], loss_acc);
            }
            int bA = posA / T_, tA2 = posA - bA * T_;
            out_idx[((size_t)(bA * NVQ_ + i) * G_ + g) * T_ + tA2] = (float)gsiA;
            int bB = posB / T_, tB2 = posB - bB * T_;
            out_idx[((size_t)(bB * NVQ_ + i) * G_ + g) * T_ + tB2] = (float)gsiB;
        }
    }
    // ---- epilogue: wave 0 writes zq (both chains) and reduces loss
    if (wu == 0) {
        const double* zA = zd + baseA;
        const double* zB = zd + baseB;
        float4 o0, o1;
        o0.x = (float)(zA[0] - rA[0]);
        o0.y = (float)(zA[1] - rA[1]);
        o0.z = (float)(zA[2] - rA[2]);
        o0.w = (float)(zA[3] - rA[3]);
        o1.x = (float)(zA[4] - rA[4]);
        o1.y = (float)(zA[5] - rA[5]);
        o1.z = (float)(zA[6] - rA[6]);
        o1.w = (float)(zA[7] - rA[7]);
        *(float4*)(zq + baseA)     = o0;
        *(float4*)(zq + baseA + 4) = o1;
        o0.x = (float)(zB[0] - rB[0]);
        o0.y = (float)(zB[1] - rB[1]);
        o0.z = (float)(zB[2] - rB[2]);
        o0.w = (float)(zB[3] - rB[3]);
        o1.x = (float)(zB[4] - rB[4]);
        o1.y = (float)(zB[5] - rB[5]);
        o1.z = (float)(zB[6] - rB[6]);
        o1.w = (float)(zB[7] - rB[7]);
        *(float4*)(zq + baseB)     = o0;
        *(float4*)(zq + baseB + 4) = o1;
#pragma unroll
        for (int off = 32; off >= 1; off >>= 1) loss_acc += __shfl_xor(loss_acc, off);
        if (lane == 0) atomicAdd(loss, loss_acc);
    }
}

// ---------------------------------------------------------------------------
// K4: proj_up + unfold scatter (fp32). pu_s NATURAL stride-8 rows (16B
// aligned -> ds_read_b128) with XOR swizzle byte^=((byte>>8)&7)<<4
// (bijective involution). Round-6 verified: ~80 µs faster than stride-9.
__device__ __forceinline__ int swz48(int byte) {
    return byte ^ (((byte >> 8) & 7) << 4);
}

__global__ __launch_bounds__(512) void k4_up(const float* __restrict__ zq,
                                             const float* __restrict__ pu,
                                             const double* __restrict__ loss,
                                             float* __restrict__ out_zq,
                                             float* __restrict__ out_loss) {
    __shared__ __align__(16) float pu_s[G_ * GD_ * 8];   // 48 KB, swizzled
    char* pb = (char*)pu_s;
    int tid = threadIdx.x;
#pragma unroll
    for (int it = 0; it < 3; it++) {
        int row = it * 512 + tid;            // 0..1535
        float4 lo = *(const float4*)(pu + (size_t)row * 8);
        float4 hi = *(const float4*)(pu + (size_t)row * 8 + 4);
        int byte0 = row * 32;
        *(float4*)(pb + swz48(byte0))      = lo;
        *(float4*)(pb + swz48(byte0 + 16)) = hi;
    }
    if (blockIdx.x == 0 && tid == 0) {
        double l = loss[0] * (1.0 / 460800.0);   // /(B*T*D) per group, /G
        out_loss[0] = (float)l;
        out_loss[1] = (float)l;
    }
    __syncthreads();
    int wv = tid >> 6, lane = tid & 63;
    int pos = blockIdx.x * 8 + wv;
    int b = pos / T_, t = pos - b * T_;
    int ov = lane >> 4, c0 = (lane & 15) * 4;
    int gd_min = ov * FIX_ + c0 * 6;
    int g_lo = gd_min >> 9;
    int g_hi = g_lo < 2 ? g_lo + 1 : 2;
    float za[8], zb[8];
    const float* zqa = zq + ((size_t)g_lo * NPOS_ + pos) * D_;
    const float* zqb = zq + ((size_t)g_hi * NPOS_ + pos) * D_;
#pragma unroll
    for (int d = 0; d < 8; d++) { za[d] = zqa[d]; zb[d] = zqb[d]; }
#pragma unroll
    for (int h = 0; h < H_; h++) {
        float4 o;
        float* op = &o.x;
#pragma unroll
        for (int q = 0; q < 4; q++) {
            int gd = ov * FIX_ + (c0 + q) * 6 + h;   // == row in pu_s
            int byte0 = gd * 32;
            float4 fa = *(const float4*)(pb + swz48(byte0));
            float4 fb = *(const float4*)(pb + swz48(byte0 + 16));
            bool hi = ((gd >> 9) != g_lo);
            const float* zv = hi ? zb : za;
            float acc = zv[0] * fa.x;
            acc = fmaf(zv[1], fa.y, acc);
            acc = fmaf(zv[2], fa.z, acc);
            acc = fmaf(zv[3], fa.w, acc);
            acc = fmaf(zv[4], fb.x, acc);
            acc = fmaf(zv[5], fb.y, acc);
            acc = fmaf(zv[6], fb.z, acc);
            acc = fmaf(zv[7], fb.w, acc);
            op[q] = acc;
        }
        *(float4*)(out_zq + ((size_t)((b * H_ + h) * W_ + 4 * t + ov)) * C_ + c0) = o;
    }
}

// ---------------------------------------------------------------------------
extern "C" void kernel_launch(void* const* d_in, const int* in_sizes, int n_in,
                              void* d_out, int out_size, void* d_ws, size_t ws_size,
                              hipStream_t stream) {
    const float* ze = (const float*)d_in[0];
    const float* pd = (const float*)d_in[1];
    const float* pu = (const float*)d_in[2];
    const float* cb = (const float*)d_in[3];
    // d_in[4] = num_streams (==6, compile-time NVQ_)

    float* out = (float*)d_out;
    char*  ws  = (char*)d_ws;
    double* ws_en   = (double*)(ws + WS_EN);
    double* ws_zd   = (double*)(ws + WS_ZD);
    double* ws_loss = (double*)(ws + WS_LOSS);
    float*  ws_zq   = (float*)(ws + WS_ZQ);
    // fp32 row-major codebook scratch inside the output zq region (576 KB),
    // fully overwritten by k4 after k3 consumes it.
    float* en32 = out + OUT_ZQ;

    k1_norm_cb<<<(G_ * NVQ_ * K_ + 255) / 256, 256, 0, stream>>>(cb, ws_en, en32, ws_loss);
    k2_fold_pd<<<NPOS_ / 8, 256, 0, stream>>>(ze, pd, ws_zd);
    k3_rvq<<<G_ * (NPOS_ / 128), 512, 0, stream>>>(ws_en, en32, ws_zd, ws_zq, ws_loss, out + OUT_IDX);
    k4_up<<<NPOS_ / 8, 512, 0, stream>>>(ws_zq, pu, ws_loss, out + OUT_ZQ, out + OUT_LOSS);
}